// Round 10
// baseline (229.433 us; speedup 1.0000x reference)
//
#include <hip/hip_runtime.h>
#include <hip/hip_bf16.h>

// CrossAttention: B=4, C=256, N=4096, OUT=256, temp=16.
// v10: TWO kernels total (residual discriminator) + 16-wave p/c flash.
//  - qkv_proj: r8 structure (LDS transpose staging, dual-path GEMM, LDS
//    out-assembly + coalesced blast) with wcvt FOLDED IN: W read as fp32,
//    converted inline (INV_TEMP folded into Wq cvt — exact, power of 2).
//  - flash_attn: 1024-thr WG (16 waves: 8 producers + 8 consumers), 1 WG/CU,
//    4 waves/SIMD (2P+2C) for latency cover. Producers: 16-key granule x
//    32-n half (16 MFMA/interval). Consumers: 32-o slice (16 MFMA/interval).
//    Same L2 ingest as r8 (64 q-rows/WG, K/V read once per WG). One barrier
//    per 64-key interval; K/V dbuf via global_load_lds; in-kernel normalize.
// Workspace: qg 8.4MB + kt 8.4MB + vt 8.4MB.

typedef __attribute__((ext_vector_type(8))) short bf16x8;
typedef __attribute__((ext_vector_type(4))) float f32x4;
typedef __attribute__((ext_vector_type(4))) short short4t;

constexpr int B_ = 4;
constexpr int C_ = 256;
constexpr int N_ = 4096;
constexpr int O_ = 256;
constexpr float INV_TEMP = 1.0f / 16.0f;
constexpr int NIT = 64;   // 64-key intervals (all 4096 keys, SPLIT=1)

__device__ __forceinline__ short f2bf(float f) {
  union { float f; unsigned u; } v; v.f = f;
  unsigned r = v.u + 0x7fffu + ((v.u >> 16) & 1u);   // RNE
  return (short)(r >> 16);
}

// async global->LDS DMA: lane i reads g + i*16B, lands at ldsbase + i*16B.
__device__ __forceinline__ void dma16(const void* g, void* l) {
  __builtin_amdgcn_global_load_lds(
      (const __attribute__((address_space(1))) unsigned int*)g,
      (__attribute__((address_space(3))) unsigned int*)l, 16, 0, 0);
}

// ---------------------------------------------------------------------------
// Projections. Grid (64, B, 3). Block 256 (4 waves). z: 0=Q, 1=K, 2=V.
// W read as fp32 + inline cvt (wcvt folded; temp folded into Wq).
// ---------------------------------------------------------------------------
__global__ __launch_bounds__(256, 2) void qkv_proj(
    const float* __restrict__ x, const float* __restrict__ xx,
    const float* __restrict__ Wq, const float* __restrict__ Wk,
    const float* __restrict__ Wv,
    short* __restrict__ qg, short* __restrict__ kt, short* __restrict__ vt) {
  const int n0  = blockIdx.x * 64;
  const int b   = blockIdx.y;
  const int mat = blockIdx.z;
  const float* src = (mat == 0) ? x : xx;
  const float* Wm  = (mat == 0) ? Wq : (mat == 1 ? Wk : Wv);
  const float ws   = (mat == 0) ? INV_TEMP : 1.0f;
  const int tid = threadIdx.x;
  const int w = tid >> 6, lane = tid & 63;
  const int g = lane >> 4, c16 = lane & 15;

  __shared__ __align__(16) short xs[64][264];   // staged tile / out assembly

  {  // transpose staging: coalesced dword loads along n, short4 LDS writes
    const int n = tid & 63, cq = tid >> 6;
    const float* sp = src + (size_t)b * C_ * N_ + n0 + n;
#pragma unroll
    for (int rep = 0; rep < 16; ++rep) {
      int c = rep * 16 + cq * 4;
      short4t s4;
#pragma unroll
      for (int j = 0; j < 4; ++j) s4[j] = f2bf(sp[(size_t)(c + j) * N_]);
      *(short4t*)&xs[n][c] = s4;
    }
  }
  __syncthreads();

  f32x4 acc[4][4];
#pragma unroll
  for (int i = 0; i < 4; ++i)
#pragma unroll
    for (int j = 0; j < 4; ++j) acc[i][j] = (f32x4){0.f, 0.f, 0.f, 0.f};

#pragma unroll
  for (int ko = 0; ko < 8; ++ko) {
    bf16x8 wfr[4], xfr[4];
#pragma unroll
    for (int ot = 0; ot < 4; ++ot) {
      const float* wp =
          Wm + (size_t)(w * 64 + ot * 16 + c16) * C_ + ko * 32 + g * 8;
      float4 f0 = *(const float4*)wp;
      float4 f1 = *(const float4*)(wp + 4);
      bf16x8 a;
      a[0] = f2bf(f0.x * ws); a[1] = f2bf(f0.y * ws);
      a[2] = f2bf(f0.z * ws); a[3] = f2bf(f0.w * ws);
      a[4] = f2bf(f1.x * ws); a[5] = f2bf(f1.y * ws);
      a[6] = f2bf(f1.z * ws); a[7] = f2bf(f1.w * ws);
      wfr[ot] = a;
    }
#pragma unroll
    for (int nt = 0; nt < 4; ++nt)
      xfr[nt] = *(const bf16x8*)&xs[nt * 16 + c16][ko * 32 + g * 8];
    if (mat < 2) {
#pragma unroll
      for (int ot = 0; ot < 4; ++ot)
#pragma unroll
        for (int nt = 0; nt < 4; ++nt)
          acc[ot][nt] = __builtin_amdgcn_mfma_f32_16x16x32_bf16(
              wfr[ot], xfr[nt], acc[ot][nt], 0, 0, 0);
    } else {  // V: swapped operands -> D rows = m, cols = o
#pragma unroll
      for (int mt = 0; mt < 4; ++mt)
#pragma unroll
        for (int ot = 0; ot < 4; ++ot)
          acc[mt][ot] = __builtin_amdgcn_mfma_f32_16x16x32_bf16(
              xfr[mt], wfr[ot], acc[mt][ot], 0, 0, 0);
    }
  }

  __syncthreads();               // xs tile reads done; reuse as out-assembly
  short* ob = &xs[0][0];         // 16384 shorts used

  if (mat == 0) {
#pragma unroll
    for (int ot = 0; ot < 4; ++ot)
#pragma unroll
      for (int nt = 0; nt < 4; ++nt) {
        int f = (nt * 16 + c16) * 256 + w * 64 + ot * 16 + g * 4;
        short4t s;
        s[0] = f2bf(acc[ot][nt][0]);
        s[1] = f2bf(acc[ot][nt][1]);
        s[2] = f2bf(acc[ot][nt][2]);
        s[3] = f2bf(acc[ot][nt][3]);
        *(short4t*)&ob[f] = s;
      }
  } else if (mat == 1) {
#pragma unroll
    for (int ot = 0; ot < 4; ++ot)
#pragma unroll
      for (int nt = 0; nt < 4; ++nt) {
        int koo = w * 2 + (ot >> 1);
        int pos = (((ot & 1) * 2 + (g >> 1)) ^ ((c16 >> 1) & 3));
        int f = nt * 4096 + koo * 512 + c16 * 32 + pos * 8 + (g & 1) * 4;
        short4t s;
        s[0] = f2bf(acc[ot][nt][0]);
        s[1] = f2bf(acc[ot][nt][1]);
        s[2] = f2bf(acc[ot][nt][2]);
        s[3] = f2bf(acc[ot][nt][3]);
        *(short4t*)&ob[f] = s;
      }
  } else {  // V: acc[mt][ot], rows m = mt*16+g*4+r, cols o = w*64+ot*16+c16
#pragma unroll
    for (int mt = 0; mt < 4; ++mt)
#pragma unroll
      for (int ot = 0; ot < 4; ++ot) {
        int o = w * 64 + ot * 16 + c16;
        int pos = (mt * 2 + (g >> 1)) ^ (o & 7);
        int f = o * 64 + pos * 8 + (g & 1) * 4;
        short4t s;
        s[0] = f2bf(acc[mt][ot][0]);
        s[1] = f2bf(acc[mt][ot][1]);
        s[2] = f2bf(acc[mt][ot][2]);
        s[3] = f2bf(acc[mt][ot][3]);
        *(short4t*)&ob[f] = s;
      }
  }
  __syncthreads();

  short* dst = (mat == 0) ? qg + ((size_t)b * N_ + n0) * O_
             : (mat == 1) ? kt + (size_t)(b * 256 + (n0 >> 4)) * 4096
                          : vt + (size_t)(b * 64 + (n0 >> 6)) * 16384;
  const uint4* s4 = (const uint4*)ob;
  uint4* d4 = (uint4*)dst;
#pragma unroll
  for (int j = 0; j < 8; ++j) d4[j * 256 + tid] = s4[j * 256 + tid];
}

// ---------------------------------------------------------------------------
// Flash attention, 16-wave p/c. Grid (8, 32). Block 1024 (16 waves).
// b = x>>1 (XCD-pinned), n0 = ((x&1)*32 + y)*64. 1 WG/CU, 4 waves/SIMD.
// Producer wave p (0..7): granule ga=p&3 (16 keys), n-half h=p>>2 (32 n).
// Consumer wave cw (0..7): o-slice cw*32 .. cw*32+31.
// LDS: kb 2x32KB + vb 2x32KB + ps 2x9.2KB + lsum 1KB = 147KB.
// ---------------------------------------------------------------------------
__global__ __launch_bounds__(1024, 4) void flash_attn(
    const short* __restrict__ qg, const short* __restrict__ kt,
    const short* __restrict__ vt, float* __restrict__ out) {
  const int xg = blockIdx.x;
  const int b  = xg >> 1;
  const int n0 = (((xg & 1) << 5) + blockIdx.y) * 64;
  const int tid = threadIdx.x;
  const int w = tid >> 6, lane = tid & 63;
  const int g = lane >> 4, c16 = lane & 15;
  const bool prod = (w < 8);
  const int ga = w & 3;            // producer granule (16 keys)
  const int h  = (w >> 2) & 1;     // producer n-half
  const int cw = w & 7;            // consumer o-slice index

  __shared__ short kb[2][16384];   // K dbuf: 64 keys x 256 o
  __shared__ short vb[2][16384];   // V dbuf: 64 m x 256 o (o-major rows)
  __shared__ short ps[2][64][72];  // P dbuf: 64 n x 64 m
  __shared__ float lsum[4][64];

  const short* ktb = kt + (size_t)b * N_ * O_;
  const short* vtb = vt + (size_t)b * N_ * O_;

  bf16x8 qf[2][8];
  float lrun[2] = {0.f, 0.f};
  f32x4 oacc[2][4];
#pragma unroll
  for (int i = 0; i < 2; ++i)
#pragma unroll
    for (int j = 0; j < 4; ++j) oacc[i][j] = (f32x4){0.f, 0.f, 0.f, 0.f};

  if (prod) {
    // Q fragments for this wave's 32 n (2 subtiles of 16)
#pragma unroll
    for (int j = 0; j < 2; ++j) {
      const short* qrow =
          qg + (size_t)(b * N_ + n0 + (h * 2 + j) * 16 + c16) * O_ + g * 8;
#pragma unroll
      for (int ko = 0; ko < 8; ++ko)
        qf[j][ko] = *(const bf16x8*)(qrow + ko * 32);
    }
    // prologue: K(0): wave p copies half-granule (p>>1, p&1)
    const short* src = ktb + (size_t)(w >> 1) * 4096 + (w & 1) * 2048;
    short* dst = &kb[0][(w >> 1) * 4096 + (w & 1) * 2048];
#pragma unroll
    for (int j = 0; j < 4; ++j)
      dma16(src + j * 512 + lane * 8, dst + j * 512);
  }
  __syncthreads();

  const int sw = (g ^ ((c16 >> 1) & 3)) * 8;   // K chunk swizzle (shorts)

  for (int i = 0; i <= NIT; ++i) {
    if (prod) {
      if (i < NIT) {
        if (i + 1 < NIT) {  // prefetch K(i+1): half-granule per wave
          const short* src =
              ktb + (size_t)(4 * (i + 1) + (w >> 1)) * 4096 + (w & 1) * 2048;
          short* dst = &kb[(i + 1) & 1][(w >> 1) * 4096 + (w & 1) * 2048];
#pragma unroll
          for (int j = 0; j < 4; ++j)
            dma16(src + j * 512 + lane * 8, dst + j * 512);
        }
        // S^T = K Q^T for granule ga (16 m), this wave's 32 n
        const short* ksl = &kb[i & 1][ga * 4096];
        f32x4 sacc[2];
        sacc[0] = (f32x4){0.f, 0.f, 0.f, 0.f};
        sacc[1] = (f32x4){0.f, 0.f, 0.f, 0.f};
#pragma unroll
        for (int ko = 0; ko < 8; ++ko) {
          bf16x8 kf = *(const bf16x8*)&ksl[(ko * 16 + c16) * 32 + sw];
#pragma unroll
          for (int j = 0; j < 2; ++j)
            sacc[j] = __builtin_amdgcn_mfma_f32_16x16x32_bf16(
                kf, qf[j][ko], sacc[j], 0, 0, 0);
        }
        // p = exp(s) (no max subtraction: |s| <= ~2.5 by construction)
#pragma unroll
        for (int j = 0; j < 2; ++j) {
          short4t pb;
          float rs = 0.f;
#pragma unroll
          for (int r = 0; r < 4; ++r) {
            float p = __expf(sacc[j][r]);
            rs += p;
            pb[r] = f2bf(p);
          }
          lrun[j] += rs;   // lane-local; folded over g at epilogue
          *(short4t*)&ps[i & 1][(h * 2 + j) * 16 + c16][ga * 16 + g * 4] = pb;
        }
      }
    } else {
      if (i < NIT) {  // prefetch V(i): 4KB per consumer wave
        const short* src = vtb + (size_t)i * 16384 + cw * 2048;
        short* dst = &vb[i & 1][cw * 2048];
#pragma unroll
        for (int j = 0; j < 4; ++j)
          dma16(src + j * 512 + lane * 8, dst + j * 512);
      }
      if (i > 0) {  // O += V(i-1) P(i-1)^T for o-slice cw
        const int pb_ = (i - 1) & 1;
#pragma unroll
        for (int kk = 0; kk < 2; ++kk) {
          bf16x8 pf[4];
#pragma unroll
          for (int nt = 0; nt < 4; ++nt)
            pf[nt] = *(const bf16x8*)&ps[pb_][nt * 16 + c16][kk * 32 + g * 8];
#pragma unroll
          for (int ot = 0; ot < 2; ++ot) {
            int o = cw * 32 + ot * 16 + c16;
            int pos = (kk * 4 + g) ^ (o & 7);
            bf16x8 vf = *(const bf16x8*)&vb[pb_][o * 64 + pos * 8];
#pragma unroll
            for (int nt = 0; nt < 4; ++nt)
              oacc[ot][nt] = __builtin_amdgcn_mfma_f32_16x16x32_bf16(
                  vf, pf[nt], oacc[ot][nt], 0, 0, 0);
          }
        }
      }
    }
    __syncthreads();
  }

  // epilogue: producers publish granule row-sums; consumers normalize+store
  if (prod) {
#pragma unroll
    for (int j = 0; j < 2; ++j) {
      float v = lrun[j];
      v += __shfl_xor(v, 16);
      v += __shfl_xor(v, 32);
      if (lane < 16) lsum[ga][h * 32 + j * 16 + lane] = v;
    }
  }
  __syncthreads();
  if (!prod) {
#pragma unroll
    for (int nt = 0; nt < 4; ++nt) {
      const int nl = nt * 16 + c16;
      float l = lsum[0][nl] + lsum[1][nl] + lsum[2][nl] + lsum[3][nl];
      float li = 1.0f / l;
#pragma unroll
      for (int ot = 0; ot < 2; ++ot) {
        float* op = out + ((size_t)b * O_ + cw * 32 + ot * 16 + g * 4) * N_ +
                    n0 + nl;
#pragma unroll
        for (int r = 0; r < 4; ++r)
          op[(size_t)r * N_] = oacc[ot][nt][r] * li;
      }
    }
  }
}

// ---------------------------------------------------------------------------
extern "C" void kernel_launch(void* const* d_in, const int* in_sizes, int n_in,
                              void* d_out, int out_size, void* d_ws,
                              size_t ws_size, hipStream_t stream) {
  const float* x  = (const float*)d_in[0];
  const float* xx = (const float*)d_in[1];
  const float* Wq = (const float*)d_in[2];
  const float* Wk = (const float*)d_in[3];
  const float* Wv = (const float*)d_in[4];
  float* out = (float*)d_out;

  short* qg = (short*)d_ws;                         // 8.39 MB
  short* kt = qg + (size_t)B_ * N_ * O_;            // 8.39 MB (tiled K)
  short* vt = kt + (size_t)B_ * N_ * O_;            // 8.39 MB (tiled V)

  qkv_proj<<<dim3(N_ / 64, B_, 3), 256, 0, stream>>>(x, xx, Wq, Wk, Wv, qg,
                                                     kt, vt);
  flash_attn<<<dim3(8, 32), 1024, 0, stream>>>(qg, kt, vt, out);
}